// Round 1
// 211.430 us; speedup vs baseline: 1.0284x; 1.0284x over previous
//
#include <hip/hip_runtime.h>
#include <stdint.h>

#define N_TOK 2048
#define DDIM 1024
#define HDIM 4096
#define NEXP 8
#define BM 128
#define MAXT 24
#define PADCAP 3072

// ctrl block layout (int offsets into d_ws)
#define C_COUNTS 0
#define C_CURSOR 8
#define C_PADOFF 16
#define C_TILECNT 25
#define C_TILE_E 32
#define C_TILE_M0 56
#define C_TILE_ROWS 80
#define C_EXPERT 128
#define C_PERM 2176            // 3072 ints

#define XG_OFF 32768                       // bf16 [PADCAP][DDIM]  = 6.29 MB
#define HG_OFF (XG_OFF + PADCAP*DDIM*2)    // bf16 [PADCAP][HDIM]  = 25.2 MB

typedef float f32x4 __attribute__((ext_vector_type(4)));
typedef short s16x8 __attribute__((ext_vector_type(8)));
typedef unsigned int u32;
typedef u32 u32x2 __attribute__((ext_vector_type(2)));
typedef unsigned short u16;

__device__ __forceinline__ u16 f2bf(float f){
  u32 u = __float_as_uint(f);
  u += 0x7fffu + ((u >> 16) & 1u);   // RNE
  return (u16)(u >> 16);
}

__device__ __forceinline__ u32 pkbf(float a, float b){   // {lo16=bf(a), hi16=bf(b)}
  u32 r; asm("v_cvt_pk_bf16_f32 %0, %1, %2" : "=v"(r) : "v"(a), "v"(b)); return r;
}

__device__ __forceinline__ void gl_lds16(const void* g, void* l){
  __builtin_amdgcn_global_load_lds((const __attribute__((address_space(1))) u32*)g,
                                   (__attribute__((address_space(3))) u32*)l, 16, 0, 0);
}

// ---------------- gating: fp32 logits, argmax (first-max tie rule), counts ---
__global__ __launch_bounds__(256) void gate_kern(
    const float* __restrict__ x, const float* __restrict__ gw,
    const float* __restrict__ gb, int* __restrict__ ctrl)
{
  const int wv = threadIdx.x >> 6, l = threadIdx.x & 63;
  const int n = blockIdx.x * 4 + wv;            // one wave per token
  const float* xr = x + (size_t)n * DDIM;
  float acc[NEXP];
  #pragma unroll
  for (int e = 0; e < NEXP; e++) acc[e] = 0.f;
  #pragma unroll 4
  for (int i = 0; i < DDIM/64; i++){
    int k = i*64 + l;
    float xv = xr[k];
    const float* g = gw + (size_t)k * NEXP;
    #pragma unroll
    for (int e = 0; e < NEXP; e++) acc[e] = fmaf(xv, g[e], acc[e]);
  }
  #pragma unroll
  for (int e = 0; e < NEXP; e++){
    #pragma unroll
    for (int off = 32; off > 0; off >>= 1) acc[e] += __shfl_xor(acc[e], off);
  }
  if (l == 0){
    float best = acc[0] + gb[0]; int bi = 0;
    #pragma unroll
    for (int e = 1; e < NEXP; e++){
      float v = acc[e] + gb[e];
      if (v > best){ best = v; bi = e; }        // strict > keeps first index
    }
    ctrl[C_EXPERT + n] = bi;
    atomicAdd(&ctrl[C_COUNTS + bi], 1);
  }
}

// ------------- setup: aux loss, padded offsets, tile table, perm init --------
__global__ void setup_kern(int* __restrict__ ctrl, float* __restrict__ aux_out)
{
  const int t = threadIdx.x;
  for (int i = t; i < PADCAP; i += 256) ctrl[C_PERM + i] = -1;
  if (t == 0){
    int off = 0, tc = 0;
    float aux = 0.f;
    for (int e = 0; e < NEXP; e++){
      int c = ctrl[C_COUNTS + e];
      ctrl[C_PADOFF + e] = off;
      ctrl[C_CURSOR + e] = off;
      int nt = (c + BM - 1) / BM;
      for (int j = 0; j < nt; j++){
        ctrl[C_TILE_E   + tc] = e;
        ctrl[C_TILE_M0  + tc] = off + j*BM;
        ctrl[C_TILE_ROWS+ tc] = min(BM, c - j*BM);
        tc++;
      }
      off += nt * BM;
      float fr = (float)c * (1.f/(float)N_TOK);
      float d = fr - 1.f/(float)NEXP;
      aux += d*d;
    }
    ctrl[C_TILECNT] = tc;
    *aux_out = aux * (1.f/(float)NEXP);
  }
}

// ------------------------- scatter tokens into grouped slots -----------------
__global__ __launch_bounds__(256) void scatter_kern(int* __restrict__ ctrl)
{
  const int n = blockIdx.x * 256 + threadIdx.x;
  const int e = ctrl[C_EXPERT + n];
  const int pos = atomicAdd(&ctrl[C_CURSOR + e], 1);
  ctrl[C_PERM + pos] = n;
}

// ------------------ gather + f32->bf16 convert of x into Xg ------------------
__global__ __launch_bounds__(256) void xg_kern(
    const float* __restrict__ x, const int* __restrict__ ctrl,
    u16* __restrict__ Xg)
{
  const int slot = blockIdx.x, t = threadIdx.x;
  const int tok = ctrl[C_PERM + slot];
  ushort4 o;
  if (tok >= 0){
    f32x4 v = *(const f32x4*)(x + (size_t)tok*DDIM + t*4);
    o.x = f2bf(v.x); o.y = f2bf(v.y); o.z = f2bf(v.z); o.w = f2bf(v.w);
  } else { o.x = 0; o.y = 0; o.z = 0; o.w = 0; }
  *(ushort4*)(Xg + (size_t)slot*DDIM + t*4) = o;
}

// --------------------------- the two FFN GEMMs -------------------------------
// MODE 1: Hg = gelu(Xg @ w1[e] + b1[e])   (K=1024, N=4096, BN=128, BK=32)
// MODE 2: out[tok] = Hg @ w2[e] + b2[e]   (K=4096, N=1024, BN=64,  BK=64, scatter)
//
// Counted-vmcnt pipeline (no full drains):
//   iter t: issue A(t+2)->As[(t+2)%3] (glds) + W(t+2)->wreg (regs)
//           COMPUTE(t)  (inputs retired last iter, no wait)
//           s_waitcnt vmcnt(VM_ITER)  -> retires only W(t+1)+A(t+1)
//           CVT W(t+1) -> Bst[(t+1)&1]
//           lgkmcnt(0); raw s_barrier   (prefetched loads stay in flight)
// Cross-wave LDS visibility: each wave retires its OWN glds via the counted
// vmcnt BEFORE the barrier, so post-barrier reads are safe.
template<int MODE>
__global__ __launch_bounds__(256, (MODE==1) ? 3 : 2) void moe_gemm(
    const u16* __restrict__ Ag, const float* __restrict__ W,
    const float* __restrict__ bias, u16* __restrict__ Hg,
    float* __restrict__ outp, const int* __restrict__ ctrl)
{
  constexpr int K   = (MODE==1) ? DDIM : HDIM;
  constexpr int NN  = (MODE==1) ? HDIM : DDIM;
  constexpr int BN  = (MODE==1) ? 128 : 64;
  constexpr int BK  = (MODE==1) ? 32 : 64;
  constexpr int BKP = (MODE==1) ? 40 : 72;  // padded rows, 16B-aligned
  constexpr int NF  = BN / 32;              // n-frags per wave: 4 / 2
  constexpr int CPR = BK / 8;               // 16B chunks per A row: 4 / 8
  constexpr int AVM = BK / 16;              // A glds per thread/iter: 2 / 4
  constexpr int NKK = BK / 32;              // mfma k-steps: 1 / 2
  constexpr int KRP = 4 * (256 / BN);       // k-rows per W pass: 8 / 16
  constexpr int NPASS = BK / KRP;           // 4 / 4
  constexpr int WREG  = 4 * NPASS;          // 16 / 16
  constexpr int NT  = K / BK;               // 32 / 64  (both even)
  // VM_ITER = WREG + AVM : 18 (MODE1) / 20 (MODE2)

  const int by = blockIdx.y;
  if (by >= ctrl[C_TILECNT]) return;
  const int e    = ctrl[C_TILE_E + by];
  const int m0   = ctrl[C_TILE_M0 + by];
  const int rows = ctrl[C_TILE_ROWS + by];
  const int n0   = blockIdx.x * BN;

  const int tid = threadIdx.x;
  const int w = tid >> 6, l = tid & 63;
  const int wr = w >> 1, wc = w & 1;
  const int lhi = l >> 4, llo = l & 15;

  __shared__ __align__(16) u16 As[3][BM*BK];     // triple buffer
  __shared__ __align__(16) u16 Bst[2][BN*BKP];
  __shared__ int perm_s[BM];

  if constexpr (MODE == 2){
    if (tid < BM) perm_s[tid] = ctrl[C_PERM + m0 + tid];
  }

  f32x4 acc[4][NF];
  #pragma unroll
  for (int mf = 0; mf < 4; mf++)
    #pragma unroll
    for (int nf = 0; nf < NF; nf++) acc[mf][nf] = (f32x4){0.f,0.f,0.f,0.f};

  const u16* Abase = Ag + (size_t)m0 * K;
  // per-thread A staging geometry: AVM chunks of 16B, chunk-XOR pre-swizzled src
  int arow[AVM], apos[AVM];
  #pragma unroll
  for (int i = 0; i < AVM; i++){
    int f = i*256 + tid;
    arow[i] = f / CPR;
    apos[i] = (f & (CPR-1)) ^ (arow[i] & (CPR-1));
  }

  // W staging geometry
  const int wn = tid & (BN-1);
  const int wkg = (tid / BN) & 3;
  const float* Wb = W + (size_t)e * K * NN + n0 + wn;
  float wregA[WREG], wregB[WREG];

#define WAITV(N) asm volatile("s_waitcnt vmcnt(" #N ")" ::: "memory")
#define WAIT_PIPE() do { if constexpr (MODE==1) WAITV(18); else WAITV(20); } while(0)
#define PIPE_BAR() do { asm volatile("s_waitcnt lgkmcnt(0)" ::: "memory"); \
    __builtin_amdgcn_sched_barrier(0); \
    __builtin_amdgcn_s_barrier(); \
    __builtin_amdgcn_sched_barrier(0); } while(0)

#define STAGE_A(buf, k0) { \
    u16* ad = &As[buf][(w*64)*8]; \
    _Pragma("unroll") \
    for (int i = 0; i < AVM; i++) \
      gl_lds16(Abase + (size_t)arow[i]*K + (k0) + apos[i]*8, ad + i*256*8); }

#define LOAD_W(dst, k0) { \
    _Pragma("unroll") \
    for (int g = 0; g < NPASS; g++){ \
      _Pragma("unroll") \
      for (int j = 0; j < 4; j++) \
        dst[g*4+j] = Wb[(size_t)((k0) + g*KRP + wkg*4 + j) * NN]; } }

#define CVT_W(buf, src) { \
    _Pragma("unroll") \
    for (int g = 0; g < NPASS; g++){ \
      u32x2 d; d.x = pkbf(src[g*4+0], src[g*4+1]); \
               d.y = pkbf(src[g*4+2], src[g*4+3]); \
      *(u32x2*)&Bst[buf][wn*BKP + g*KRP + wkg*4] = d; } }

#define COMPUTE(abuf, bbuf) { \
    __builtin_amdgcn_s_setprio(1); \
    _Pragma("unroll") \
    for (int kk = 0; kk < NKK; kk++){ \
      s16x8 a[4], b[NF]; \
      _Pragma("unroll") \
      for (int mf = 0; mf < 4; mf++){ \
        int row = wr*64 + mf*16 + llo; \
        int pos = ((kk<<2) | lhi) ^ (row & (CPR-1)); \
        a[mf] = *(const s16x8*)&As[abuf][row*BK + pos*8]; } \
      _Pragma("unroll") \
      for (int nf = 0; nf < NF; nf++){ \
        int col = wc*(BN/2) + nf*16 + llo; \
        b[nf] = *(const s16x8*)&Bst[bbuf][col*BKP + kk*32 + lhi*8]; } \
      _Pragma("unroll") \
      for (int mf = 0; mf < 4; mf++) \
        _Pragma("unroll") \
        for (int nf = 0; nf < NF; nf++) \
          acc[mf][nf] = __builtin_amdgcn_mfma_f32_16x16x32_bf16(a[mf], b[nf], acc[mf][nf], 0, 0, 0); } \
    __builtin_amdgcn_s_setprio(0); }

#define ITER(tt, LD, CV) { \
    if ((tt)+2 < NT){ \
      LOAD_W(LD, ((tt)+2)*BK); \
      STAGE_A(((tt)+2)%3, ((tt)+2)*BK); \
    } \
    COMPUTE((tt)%3, (tt)&1); \
    if ((tt)+2 < NT){ WAIT_PIPE(); } else { WAITV(0); } \
    if ((tt)+1 < NT){ CVT_W(((tt)+1)&1, CV); } \
    PIPE_BAR(); }

  // prologue: tiles 0 and 1 in flight; convert W(0); leave W(1)+A(1) pending
  LOAD_W(wregA, 0);
  STAGE_A(0, 0);
  LOAD_W(wregB, BK);
  STAGE_A(1, BK);
  WAIT_PIPE();              // retires W(0)+A(0); W(1)+A(1) stay in flight
  CVT_W(0, wregA);
  PIPE_BAR();

  #pragma unroll 1
  for (int t = 0; t < NT; t += 2){
    ITER(t,   wregA, wregB);   // even: loads -> wregA, converts wregB=W(t+1)
    ITER(t+1, wregB, wregA);   // odd : loads -> wregB, converts wregA
  }

  if constexpr (MODE == 1){
    const float* bp = bias + (size_t)e*NN + n0;
    #pragma unroll
    for (int nf = 0; nf < NF; nf++){
      const int cl = wc*(BN/2) + nf*16 + llo;
      const float bb = bp[cl];
      #pragma unroll
      for (int mf = 0; mf < 4; mf++){
        #pragma unroll
        for (int r = 0; r < 4; r++){
          const int rl = wr*64 + mf*16 + lhi*4 + r;
          float vv = acc[mf][nf][r] + bb;
          float gel = 0.5f * vv * (1.0f + erff(vv * 0.70710678118f)); // exact gelu
          Hg[(size_t)(m0+rl)*NN + n0 + cl] = f2bf(gel);
        }
      }
    }
  } else {
    const float* bp = bias + (size_t)e*NN + n0;
    #pragma unroll
    for (int mf = 0; mf < 4; mf++){
      #pragma unroll
      for (int r = 0; r < 4; r++){
        const int rl = wr*64 + mf*16 + lhi*4 + r;
        if (rl < rows){
          const int tok = perm_s[rl];
          #pragma unroll
          for (int nf = 0; nf < NF; nf++){
            const int cl = wc*(BN/2) + nf*16 + llo;
            outp[(size_t)tok*DDIM + n0 + cl] = acc[mf][nf][r] + bp[cl];
          }
        }
      }
    }
  }
#undef WAITV
#undef WAIT_PIPE
#undef PIPE_BAR
#undef STAGE_A
#undef LOAD_W
#undef CVT_W
#undef COMPUTE
#undef ITER
}

extern "C" void kernel_launch(void* const* d_in, const int* in_sizes, int n_in,
                              void* d_out, int out_size, void* d_ws, size_t ws_size,
                              hipStream_t stream)
{
  (void)in_sizes; (void)n_in; (void)out_size; (void)ws_size;
  const float* x  = (const float*)d_in[0];
  const float* gw = (const float*)d_in[1];
  const float* gb = (const float*)d_in[2];
  const float* w1 = (const float*)d_in[3];
  const float* b1 = (const float*)d_in[4];
  const float* w2 = (const float*)d_in[5];
  const float* b2 = (const float*)d_in[6];
  float* out = (float*)d_out;
  char* ws = (char*)d_ws;
  int* ctrl = (int*)ws;
  u16* Xg = (u16*)(ws + XG_OFF);
  u16* Hg = (u16*)(ws + HG_OFF);

  hipMemsetAsync(ctrl, 0, 64, stream);                       // counts
  gate_kern<<<N_TOK/4, 256, 0, stream>>>(x, gw, gb, ctrl);
  setup_kern<<<1, 256, 0, stream>>>(ctrl, out + (size_t)N_TOK*DDIM);
  scatter_kern<<<N_TOK/256, 256, 0, stream>>>(ctrl);
  xg_kern<<<PADCAP, 256, 0, stream>>>(x, ctrl, Xg);
  moe_gemm<1><<<dim3(HDIM/128, MAXT), 256, 0, stream>>>(Xg, w1, b1, Hg, nullptr, ctrl);
  moe_gemm<2><<<dim3(DDIM/64,  MAXT), 256, 0, stream>>>(Hg, w2, b2, nullptr, out, ctrl);
}

// Round 2
// 207.855 us; speedup vs baseline: 1.0461x; 1.0172x over previous
//
#include <hip/hip_runtime.h>
#include <stdint.h>

#define N_TOK 2048
#define DDIM 1024
#define HDIM 4096
#define NEXP 8
#define BM 128
#define MAXT 24
#define PADCAP 3072

// ctrl block layout (int offsets into d_ws)
#define C_COUNTS 0
#define C_CURSOR 8
#define C_PADOFF 16
#define C_TILECNT 25
#define C_TILE_E 32
#define C_TILE_M0 56
#define C_TILE_ROWS 80
#define C_EXPERT 128
#define C_PERM 2176            // 3072 ints

#define XG_OFF 32768                       // bf16 [PADCAP][DDIM]  = 6.29 MB
#define HG_OFF (XG_OFF + PADCAP*DDIM*2)    // bf16 [PADCAP][HDIM]  = 25.2 MB

typedef float f32x4 __attribute__((ext_vector_type(4)));
typedef short s16x8 __attribute__((ext_vector_type(8)));
typedef unsigned int u32;
typedef unsigned short u16;

__device__ __forceinline__ u16 f2bf(float f){
  u32 u = __float_as_uint(f);
  u += 0x7fffu + ((u >> 16) & 1u);   // RNE
  return (u16)(u >> 16);
}

__device__ __forceinline__ u32 pkbf(float a, float b){   // {lo16=bf(a), hi16=bf(b)}
  u32 r; asm("v_cvt_pk_bf16_f32 %0, %1, %2" : "=v"(r) : "v"(a), "v"(b)); return r;
}

__device__ __forceinline__ void gl_lds16(const void* g, void* l){
  __builtin_amdgcn_global_load_lds((const __attribute__((address_space(1))) u32*)g,
                                   (__attribute__((address_space(3))) u32*)l, 16, 0, 0);
}

// ---------------- gating: fp32 logits, argmax (first-max tie rule), counts ---
__global__ __launch_bounds__(256) void gate_kern(
    const float* __restrict__ x, const float* __restrict__ gw,
    const float* __restrict__ gb, int* __restrict__ ctrl)
{
  const int wv = threadIdx.x >> 6, l = threadIdx.x & 63;
  const int n = blockIdx.x * 4 + wv;            // one wave per token
  const float* xr = x + (size_t)n * DDIM;
  float acc[NEXP];
  #pragma unroll
  for (int e = 0; e < NEXP; e++) acc[e] = 0.f;
  #pragma unroll 4
  for (int i = 0; i < DDIM/64; i++){
    int k = i*64 + l;
    float xv = xr[k];
    const float* g = gw + (size_t)k * NEXP;
    #pragma unroll
    for (int e = 0; e < NEXP; e++) acc[e] = fmaf(xv, g[e], acc[e]);
  }
  #pragma unroll
  for (int e = 0; e < NEXP; e++){
    #pragma unroll
    for (int off = 32; off > 0; off >>= 1) acc[e] += __shfl_xor(acc[e], off);
  }
  if (l == 0){
    float best = acc[0] + gb[0]; int bi = 0;
    #pragma unroll
    for (int e = 1; e < NEXP; e++){
      float v = acc[e] + gb[e];
      if (v > best){ best = v; bi = e; }        // strict > keeps first index
    }
    ctrl[C_EXPERT + n] = bi;
    atomicAdd(&ctrl[C_COUNTS + bi], 1);
  }
}

// ------------- setup: aux loss, padded offsets, tile table, perm init --------
__global__ void setup_kern(int* __restrict__ ctrl, float* __restrict__ aux_out)
{
  const int t = threadIdx.x;
  for (int i = t; i < PADCAP; i += 256) ctrl[C_PERM + i] = -1;
  if (t == 0){
    int off = 0, tc = 0;
    float aux = 0.f;
    for (int e = 0; e < NEXP; e++){
      int c = ctrl[C_COUNTS + e];
      ctrl[C_PADOFF + e] = off;
      ctrl[C_CURSOR + e] = off;
      int nt = (c + BM - 1) / BM;
      for (int j = 0; j < nt; j++){
        ctrl[C_TILE_E   + tc] = e;
        ctrl[C_TILE_M0  + tc] = off + j*BM;
        ctrl[C_TILE_ROWS+ tc] = min(BM, c - j*BM);
        tc++;
      }
      off += nt * BM;
      float fr = (float)c * (1.f/(float)N_TOK);
      float d = fr - 1.f/(float)NEXP;
      aux += d*d;
    }
    ctrl[C_TILECNT] = tc;
    *aux_out = aux * (1.f/(float)NEXP);
  }
}

// ------------------------- scatter tokens into grouped slots -----------------
__global__ __launch_bounds__(256) void scatter_kern(int* __restrict__ ctrl)
{
  const int n = blockIdx.x * 256 + threadIdx.x;
  const int e = ctrl[C_EXPERT + n];
  const int pos = atomicAdd(&ctrl[C_CURSOR + e], 1);
  ctrl[C_PERM + pos] = n;
}

// ------------------ gather + f32->bf16 convert of x into Xg ------------------
__global__ __launch_bounds__(256) void xg_kern(
    const float* __restrict__ x, const int* __restrict__ ctrl,
    u16* __restrict__ Xg)
{
  const int slot = blockIdx.x, t = threadIdx.x;
  const int tok = ctrl[C_PERM + slot];
  ushort4 o;
  if (tok >= 0){
    f32x4 v = *(const f32x4*)(x + (size_t)tok*DDIM + t*4);
    o.x = f2bf(v.x); o.y = f2bf(v.y); o.z = f2bf(v.z); o.w = f2bf(v.w);
  } else { o.x = 0; o.y = 0; o.z = 0; o.w = 0; }
  *(ushort4*)(Xg + (size_t)slot*DDIM + t*4) = o;
}

// --------------------------- the two FFN GEMMs -------------------------------
// MODE 1: Hg = gelu(Xg @ w1[e] + b1[e])   (K=1024, N=4096, BN=128, BK=32)
// MODE 2: out[tok] = Hg @ w2[e] + b2[e]   (K=4096, N=1024, BN=64,  BK=64, scatter)
//
// Both A (bf16) and W (raw fp32) are staged via global_load_lds dwordx4
// (1 KB/wave-instr, linear LDS dest). The k-transpose of W happens on the
// LDS-read side: each B-fragment = 8 stride-BN ds_read_b32 + 4 cvt_pk.
// Chunk-XOR (bit2, both-sides) on the W tile drops the lhi-group bank
// conflict from 4-way to 2-way (free). Simple 2-phase double buffer.
template<int MODE>
__global__ __launch_bounds__(256, (MODE==1) ? 3 : 2) void moe_gemm(
    const u16* __restrict__ Ag, const float* __restrict__ W,
    const float* __restrict__ bias, u16* __restrict__ Hg,
    float* __restrict__ outp, const int* __restrict__ ctrl)
{
  constexpr int K    = (MODE==1) ? DDIM : HDIM;
  constexpr int NN   = (MODE==1) ? HDIM : DDIM;
  constexpr int BN   = (MODE==1) ? 128 : 64;
  constexpr int BK   = (MODE==1) ? 32 : 64;
  constexpr int NF   = BN / 32;              // n-frags per wave: 4 / 2
  constexpr int NKK  = BK / 32;              // mfma k-steps: 1 / 2
  constexpr int CPR  = BK / 8;               // A 16B-chunks per row: 4 / 8
  constexpr int AVM  = (BM*BK)/(256*8);      // A glds per thread: 2 / 4
  constexpr int BCPR = BN / 4;               // W 16B-chunks per row: 32 / 16
  constexpr int BVM  = (BK*BN)/(256*4);      // W glds per thread: 4 / 4
  constexpr int NT   = K / BK;               // 32 / 64

  const int by = blockIdx.y;
  if (by >= ctrl[C_TILECNT]) return;
  const int e    = ctrl[C_TILE_E + by];
  const int m0   = ctrl[C_TILE_M0 + by];
  const int rows = ctrl[C_TILE_ROWS + by];
  const int n0   = blockIdx.x * BN;

  const int tid = threadIdx.x;
  const int w = tid >> 6, l = tid & 63;
  const int wr = w >> 1, wc = w & 1;
  const int lhi = l >> 4, llo = l & 15;

  __shared__ __align__(16) u16   As[2][BM*BK];   // bf16 A tile
  __shared__ __align__(16) float Bs[2][BK*BN];   // fp32 W tile
  __shared__ int perm_s[BM];

  if constexpr (MODE == 2){
    if (tid < BM) perm_s[tid] = ctrl[C_PERM + m0 + tid];
  }

  f32x4 acc[4][NF];
  #pragma unroll
  for (int mf = 0; mf < 4; mf++)
    #pragma unroll
    for (int nf = 0; nf < NF; nf++) acc[mf][nf] = (f32x4){0.f,0.f,0.f,0.f};

  const u16* Abase = Ag + (size_t)m0 * K;
  // A staging: AVM chunks of 16B, chunk-XOR pre-swizzled src (as before)
  int arow[AVM], apos[AVM];
  #pragma unroll
  for (int i = 0; i < AVM; i++){
    int f = i*256 + tid;
    arow[i] = f / CPR;
    apos[i] = (f & (CPR-1)) ^ (arow[i] & (CPR-1));
  }
  // W staging: BVM chunks of 16B; LDS slot (r,c) holds global chunk c^SW(r),
  // SW(r) = ((r>>3)&1)<<2  (flips chunk bit2 for odd k-octets)
  const float* Wb = W + (size_t)e * K * NN + n0;
  int brow[BVM], bpos[BVM];
  #pragma unroll
  for (int i = 0; i < BVM; i++){
    int f = i*256 + tid;
    brow[i] = f / BCPR;
    bpos[i] = (f % BCPR) ^ (((brow[i] >> 3) & 1) << 2);
  }

  const int col0 = wc*(BN/2) + llo;     // this lane's base output column
  const int bswz = (lhi & 1) << 2;      // read-side chunk swizzle (matches SW)

#define STAGE_A(buf, k0) { \
    u16* ad = &As[buf][(w*64)*8]; \
    _Pragma("unroll") \
    for (int i = 0; i < AVM; i++) \
      gl_lds16(Abase + (size_t)arow[i]*K + (k0) + apos[i]*8, ad + i*256*8); }

#define STAGE_B(buf, k0) { \
    float* bd = &Bs[buf][(w*64)*4]; \
    _Pragma("unroll") \
    for (int i = 0; i < BVM; i++) \
      gl_lds16(Wb + (size_t)((k0) + brow[i])*NN + bpos[i]*4, bd + i*256*4); }

#define COMPUTE(buf) { \
    _Pragma("unroll") \
    for (int kk = 0; kk < NKK; kk++){ \
      s16x8 a[4]; \
      _Pragma("unroll") \
      for (int mf = 0; mf < 4; mf++){ \
        int row = wr*64 + mf*16 + llo; \
        int pos = ((kk<<2) | lhi) ^ (row & (CPR-1)); \
        a[mf] = *(const s16x8*)&As[buf][row*BK + pos*8]; } \
      _Pragma("unroll") \
      for (int nf = 0; nf < NF; nf++){ \
        const int col = col0 + nf*16; \
        const float* bp_ = &Bs[buf][(kk*32 + lhi*8)*BN + \
                                    ((((col) >> 2) ^ bswz) << 2) + ((col) & 3)]; \
        union { u32 u[4]; s16x8 v; } bb_; \
        bb_.u[0] = pkbf(bp_[0*BN], bp_[1*BN]); \
        bb_.u[1] = pkbf(bp_[2*BN], bp_[3*BN]); \
        bb_.u[2] = pkbf(bp_[4*BN], bp_[5*BN]); \
        bb_.u[3] = pkbf(bp_[6*BN], bp_[7*BN]); \
        _Pragma("unroll") \
        for (int mf = 0; mf < 4; mf++) \
          acc[mf][nf] = __builtin_amdgcn_mfma_f32_16x16x32_bf16(a[mf], bb_.v, acc[mf][nf], 0, 0, 0); \
      } } }

  // prologue: fill buffer 0 (syncthreads drains vmcnt before compute)
  STAGE_A(0, 0);
  STAGE_B(0, 0);
  __syncthreads();

  int cur = 0;
  #pragma unroll 1
  for (int t = 0; t < NT; t++){
    if (t+1 < NT){
      STAGE_A(cur^1, (t+1)*BK);
      STAGE_B(cur^1, (t+1)*BK);
    }
    COMPUTE(cur);
    __syncthreads();
    cur ^= 1;
  }

  if constexpr (MODE == 1){
    const float* bp = bias + (size_t)e*NN + n0;
    #pragma unroll
    for (int nf = 0; nf < NF; nf++){
      const int cl = wc*(BN/2) + nf*16 + llo;
      const float bb = bp[cl];
      #pragma unroll
      for (int mf = 0; mf < 4; mf++){
        #pragma unroll
        for (int r = 0; r < 4; r++){
          const int rl = wr*64 + mf*16 + lhi*4 + r;
          float vv = acc[mf][nf][r] + bb;
          float gel = 0.5f * vv * (1.0f + erff(vv * 0.70710678118f)); // exact gelu
          Hg[(size_t)(m0+rl)*NN + n0 + cl] = f2bf(gel);
        }
      }
    }
  } else {
    const float* bp = bias + (size_t)e*NN + n0;
    #pragma unroll
    for (int mf = 0; mf < 4; mf++){
      #pragma unroll
      for (int r = 0; r < 4; r++){
        const int rl = wr*64 + mf*16 + lhi*4 + r;
        if (rl < rows){
          const int tok = perm_s[rl];
          #pragma unroll
          for (int nf = 0; nf < NF; nf++){
            const int cl = wc*(BN/2) + nf*16 + llo;
            outp[(size_t)tok*DDIM + n0 + cl] = acc[mf][nf][r] + bp[cl];
          }
        }
      }
    }
  }
#undef STAGE_A
#undef STAGE_B
#undef COMPUTE
}

extern "C" void kernel_launch(void* const* d_in, const int* in_sizes, int n_in,
                              void* d_out, int out_size, void* d_ws, size_t ws_size,
                              hipStream_t stream)
{
  (void)in_sizes; (void)n_in; (void)out_size; (void)ws_size;
  const float* x  = (const float*)d_in[0];
  const float* gw = (const float*)d_in[1];
  const float* gb = (const float*)d_in[2];
  const float* w1 = (const float*)d_in[3];
  const float* b1 = (const float*)d_in[4];
  const float* w2 = (const float*)d_in[5];
  const float* b2 = (const float*)d_in[6];
  float* out = (float*)d_out;
  char* ws = (char*)d_ws;
  int* ctrl = (int*)ws;
  u16* Xg = (u16*)(ws + XG_OFF);
  u16* Hg = (u16*)(ws + HG_OFF);

  hipMemsetAsync(ctrl, 0, 64, stream);                       // counts
  gate_kern<<<N_TOK/4, 256, 0, stream>>>(x, gw, gb, ctrl);
  setup_kern<<<1, 256, 0, stream>>>(ctrl, out + (size_t)N_TOK*DDIM);
  scatter_kern<<<N_TOK/256, 256, 0, stream>>>(ctrl);
  xg_kern<<<PADCAP, 256, 0, stream>>>(x, ctrl, Xg);
  moe_gemm<1><<<dim3(HDIM/128, MAXT), 256, 0, stream>>>(Xg, w1, b1, Hg, nullptr, ctrl);
  moe_gemm<2><<<dim3(DDIM/64,  MAXT), 256, 0, stream>>>(Hg, w2, b2, nullptr, out, ctrl);
}